// Round 2
// baseline (398.646 us; speedup 1.0000x reference)
//
#include <hip/hip_runtime.h>
#include <hip/hip_cooperative_groups.h>
#include <math.h>

namespace cg = cooperative_groups;

#define SEQ  2048
#define ROWS 4096
#define D0   512
#define D1   64
#define C2S  524288

typedef short bf8 __attribute__((ext_vector_type(8)));   // 8 bf16 = 4 VGPRs
typedef float f4  __attribute__((ext_vector_type(4)));   // MFMA acc

// fp32 -> bf16 (RNE) and hi/lo split
__device__ __forceinline__ unsigned short f2bf(float f) {
    unsigned u = __float_as_uint(f);
    return (unsigned short)((u + 0x7fffu + ((u >> 16) & 1u)) >> 16);
}
__device__ __forceinline__ float bf2f(unsigned short u) {
    return __uint_as_float((unsigned)u << 16);
}
__device__ __forceinline__ void hilo(float f, unsigned short& h, unsigned short& l) {
    h = f2bf(f);
    float fh = bf2f(h);
    l = f2bf(f - fh);
}
__device__ __forceinline__ void cv4h(unsigned short* dh, int idx, float4 v) {
    ushort4 hv;
    hv.x = f2bf(v.x); hv.y = f2bf(v.y); hv.z = f2bf(v.z); hv.w = f2bf(v.w);
    *(ushort4*)(dh + idx) = hv;
}

// async global->LDS 16B (dest = wave-uniform base + lane*16)
__device__ __forceinline__ void async16(const void* g, void* l) {
    __builtin_amdgcn_global_load_lds(
        (const __attribute__((address_space(1))) unsigned int*)g,
        (__attribute__((address_space(3))) unsigned int*)l, 16, 0, 0);
}

// ===========================================================================
// Megakernel phase bodies (verbatim transplants of the verified kernels)
// ===========================================================================
struct KArgs {
    const float *x, *W1, *g1, *b1, *A1, *B1;
    const float *M2, *g2, *b2, *P2, *R2;
    const float *W3, *g3, *b3, *A3, *B3, *R3;
    float* out;
    float* ws;
};

// conv phase: one virtual block c (0..1343), 256 lanes (tid)
__device__ __forceinline__ void conv_v(int c, int tid, const KArgs& a,
        unsigned short* xh, unsigned short* W1h,
        unsigned short* C2h, unsigned short* C3h,
        float* A1T, float* A3T) {
    if (c < 1216) {
        const float* src; unsigned short* dh; int off;
        if      (c < 1024) { src = a.x;  dh = xh;          off = c; }
        else if (c < 1152) { src = a.W1; dh = W1h;         off = c - 1024; }
        else if (c < 1168) { src = a.M2; dh = C2h;         off = c - 1152; }
        else if (c < 1184) { src = a.R2; dh = C2h + 32768; off = c - 1168; }
        else if (c < 1200) { src = a.W3; dh = C3h;         off = c - 1184; }
        else               { src = a.R3; dh = C3h + 32768; off = c - 1200; }
        int base = off * 2048 + tid * 4;
        cv4h(dh, base,        *(const float4*)(src + base));
        cv4h(dh, base + 1024, *(const float4*)(src + base + 1024));
    } else {
        int gid = (c - 1216) * 256 + tid;     // 0..32767
        int i = gid >> 6, j = gid & 63;       // A (512 x 64)
        A1T[j * 512 + i] = a.A1[gid];
        A3T[j * 512 + i] = a.A3[gid];
    }
}

// GEMM 128(M) x 64(N per half) tile. Full 512-thread block: A-tile staged
// cooperatively by all 8 waves (both halves share bm,k0); W per half.
// OM: 0 fp32 C partial, 1 bf16 C partial, 2 mixed (bn<512 bf16 / >=512 fp32).
template<bool ALO, int OM>
__device__ __forceinline__ void gemm512(
        const unsigned short* __restrict__ Ah, const unsigned short* __restrict__ Al,
        const unsigned short* __restrict__ Wh,
        float* __restrict__ Cf, unsigned short* __restrict__ Cb,
        int N, int K, int Ks, int bm, int bn, int k0,
        unsigned short* aH, unsigned short* aL, unsigned short* wHh) {
    const int t   = threadIdx.x;          // 0..511
    const int tid = t & 255;
    const int ln  = t & 63;
    const int wv  = (t >> 6) & 3;         // wave within half
    const int lm  = ln & 15;
    const int lq  = ln >> 4;

    f4 acc[2][4] = {};

    for (int kt = 0; kt < Ks; kt += 64) {
        const int kg = k0 + kt;
        __syncthreads();
        // A staging: 1024 slots (128 rows x 64 k), 512 threads -> 2 each
#pragma unroll
        for (int i = 0; i < 2; ++i) {
            int slot = i * 512 + t;
            int row  = slot >> 3;
            int ch   = (slot & 7) ^ (row & 7);
            size_t go = (size_t)(bm + row) * K + kg + ch * 8;
            async16(Ah + go, aH + slot * 8);
            if constexpr (ALO) async16(Al + go, aL + slot * 8);
        }
        // W staging: 512 slots (64 rows x 64 k) per half, 256 threads -> 2 each
#pragma unroll
        for (int i = 0; i < 2; ++i) {
            int slot = i * 256 + tid;
            int row  = slot >> 3;
            int ch   = (slot & 7) ^ (row & 7);
            size_t go = (size_t)(bn + row) * K + kg + ch * 8;
            async16(Wh + go, wHh + slot * 8);
        }
        __syncthreads();

#pragma unroll
        for (int kk = 0; kk < 2; ++kk) {
            const int ck = kk * 4 + lq;          // 16B chunk index in k
            bf8 a_h[2], a_l[2], b_h[4];
#pragma unroll
            for (int t2 = 0; t2 < 2; ++t2) {
                int r = wv * 32 + t2 * 16 + lm;
                a_h[t2] = *(const bf8*)(aH + r * 64 + ((ck ^ (r & 7)) * 8));
                if constexpr (ALO)
                    a_l[t2] = *(const bf8*)(aL + r * 64 + ((ck ^ (r & 7)) * 8));
            }
#pragma unroll
            for (int u = 0; u < 4; ++u) {
                int rb = u * 16 + lm;
                b_h[u] = *(const bf8*)(wHh + rb * 64 + ((ck ^ (rb & 7)) * 8));
            }
#pragma unroll
            for (int t2 = 0; t2 < 2; ++t2)
#pragma unroll
                for (int u = 0; u < 4; ++u) {
                    acc[t2][u] = __builtin_amdgcn_mfma_f32_16x16x32_bf16(a_h[t2], b_h[u], acc[t2][u], 0, 0, 0);
                    if constexpr (ALO)
                        acc[t2][u] = __builtin_amdgcn_mfma_f32_16x16x32_bf16(a_l[t2], b_h[u], acc[t2][u], 0, 0, 0);
                }
        }
    }

    // C/D layout (verified): col = lane&15, row = quad*4 + reg
#pragma unroll
    for (int t2 = 0; t2 < 2; ++t2)
#pragma unroll
        for (int u = 0; u < 4; ++u) {
            int row = bm + wv * 32 + t2 * 16 + lq * 4;
            int col = bn + u * 16 + lm;
#pragma unroll
            for (int r = 0; r < 4; ++r) {
                float v = acc[t2][u][r];
                if constexpr (OM == 0) {
                    Cf[(size_t)(row + r) * N + col] = v;
                } else if constexpr (OM == 1) {
                    Cb[(size_t)(row + r) * N + col] = f2bf(v);
                } else {
                    if (col < 512) Cb[(size_t)(row + r) * 512 + col] = f2bf(v);
                    else           Cf[(size_t)(row + r) * 512 + col - 512] = v;
                }
            }
        }
}

// LN + rank-1 RN epilogue: one row per wave; vb in [0,1024), row = vb*4+wave
__device__ __forceinline__ void lnrn_v(int vb,
        const unsigned short* __restrict__ Yb0,
        const unsigned short* __restrict__ Yb1,
        const float* __restrict__ RES,
        const float* __restrict__ g, const float* __restrict__ be,
        const float* __restrict__ Bb, const float* __restrict__ AaT,
        float* __restrict__ outf,
        unsigned short* __restrict__ outh, unsigned short* __restrict__ outl) {
    const int row = vb * 4 + ((threadIdx.x >> 6) & 3);
    const int l = threadIdx.x & 63;
    const int c = l * 8;
    ushort4 ua = *(const ushort4*)(Yb0 + (size_t)row * D0 + c);
    ushort4 ub = *(const ushort4*)(Yb0 + (size_t)row * D0 + c + 4);
    float4 y0, y1;
    y0.x = bf2f(ua.x); y0.y = bf2f(ua.y); y0.z = bf2f(ua.z); y0.w = bf2f(ua.w);
    y1.x = bf2f(ub.x); y1.y = bf2f(ub.y); y1.z = bf2f(ub.z); y1.w = bf2f(ub.w);
    if (Yb1) {
        ushort4 va = *(const ushort4*)(Yb1 + (size_t)row * D0 + c);
        ushort4 vb2 = *(const ushort4*)(Yb1 + (size_t)row * D0 + c + 4);
        y0.x += bf2f(va.x); y0.y += bf2f(va.y); y0.z += bf2f(va.z); y0.w += bf2f(va.w);
        y1.x += bf2f(vb2.x); y1.y += bf2f(vb2.y); y1.z += bf2f(vb2.z); y1.w += bf2f(vb2.w);
    }
    float sum = y0.x + y0.y + y0.z + y0.w + y1.x + y1.y + y1.z + y1.w;
    float ssq = y0.x*y0.x + y0.y*y0.y + y0.z*y0.z + y0.w*y0.w
              + y1.x*y1.x + y1.y*y1.y + y1.z*y1.z + y1.w*y1.w;
#pragma unroll
    for (int m = 1; m < 64; m <<= 1) {
        sum += __shfl_xor(sum, m, 64);
        ssq += __shfl_xor(ssq, m, 64);
    }
    float mean = sum * (1.0f / 512.0f);
    float var  = ssq * (1.0f / 512.0f) - mean * mean;
    float rstd = rsqrtf(var + 1e-5f);
    float4 g0 = *(const float4*)(g + c),  g1v = *(const float4*)(g + c + 4);
    float4 e0 = *(const float4*)(be + c), e1  = *(const float4*)(be + c + 4);
    float4 n0, n1;
    n0.x = (y0.x - mean) * rstd * g0.x  + e0.x;
    n0.y = (y0.y - mean) * rstd * g0.y  + e0.y;
    n0.z = (y0.z - mean) * rstd * g0.z  + e0.z;
    n0.w = (y0.w - mean) * rstd * g0.w  + e0.w;
    n1.x = (y1.x - mean) * rstd * g1v.x + e1.x;
    n1.y = (y1.y - mean) * rstd * g1v.y + e1.y;
    n1.z = (y1.z - mean) * rstd * g1v.z + e1.z;
    n1.w = (y1.w - mean) * rstd * g1v.w + e1.w;
    const int jm = row & 63;
    const float* bb = Bb + jm * D0 + c;
    float4 b0 = *(const float4*)bb, b1v = *(const float4*)(bb + 4);
    float p = n0.x*b0.x + n0.y*b0.y + n0.z*b0.z + n0.w*b0.w
            + n1.x*b1v.x + n1.y*b1v.y + n1.z*b1v.z + n1.w*b1v.w;
#pragma unroll
    for (int m = 1; m < 64; m <<= 1) p += __shfl_xor(p, m, 64);
    const float* av = AaT + jm * D0 + c;
    float4 a0 = *(const float4*)av, a1 = *(const float4*)(av + 4);
    const float* rs = RES + (size_t)row * D0 + c;
    float4 r0 = *(const float4*)rs, r1 = *(const float4*)(rs + 4);
    float4 v0, v1;
    v0.x = p*a0.x + r0.x; v0.y = p*a0.y + r0.y; v0.z = p*a0.z + r0.z; v0.w = p*a0.w + r0.w;
    v1.x = p*a1.x + r1.x; v1.y = p*a1.y + r1.y; v1.z = p*a1.z + r1.z; v1.w = p*a1.w + r1.w;
    if (outf) {
        *(float4*)(outf + (size_t)row * D0 + c)     = v0;
        *(float4*)(outf + (size_t)row * D0 + c + 4) = v1;
    } else {
        ushort4 h0, l0, h1, l1;
        hilo(v0.x, h0.x, l0.x); hilo(v0.y, h0.y, l0.y);
        hilo(v0.z, h0.z, l0.z); hilo(v0.w, h0.w, l0.w);
        hilo(v1.x, h1.x, l1.x); hilo(v1.y, h1.y, l1.y);
        hilo(v1.z, h1.z, l1.z); hilo(v1.w, h1.w, l1.w);
        *(ushort4*)(outh + (size_t)row * D0 + c)     = h0;
        *(ushort4*)(outl + (size_t)row * D0 + c)     = l0;
        *(ushort4*)(outh + (size_t)row * D0 + c + 4) = h1;
        *(ushort4*)(outl + (size_t)row * D0 + c + 4) = l1;
    }
}

// lnt: sum 4 split-K partials, LN y-half -> t, sum residual -> rsum
__device__ __forceinline__ void lnt_v(int vb,
        const float* __restrict__ C2, const float* __restrict__ g2,
        const float* __restrict__ b2,
        float* __restrict__ tv, float* __restrict__ rsum) {
    const int r = vb * 4 + ((threadIdx.x >> 6) & 3);   // 0..4095
    const int j = threadIdx.x & 63;
    size_t base = (size_t)r * 128 + j;
    float v = 0.f, rv = 0.f;
#pragma unroll
    for (int z = 0; z < 4; ++z) {
        v  += C2[(size_t)z * C2S + base];
        rv += C2[(size_t)z * C2S + base + 64];
    }
    float sum = v, ssq = v * v;
#pragma unroll
    for (int m = 1; m < 64; m <<= 1) {
        sum += __shfl_xor(sum, m, 64);
        ssq += __shfl_xor(ssq, m, 64);
    }
    float mean = sum * (1.0f / 64.0f);
    float var  = ssq * (1.0f / 64.0f) - mean * mean;
    float rstd = rsqrtf(var + 1e-5f);
    tv[r * 64 + j]   = (v - mean) * rstd * g2[j] + b2[j];
    rsum[r * 64 + j] = rv;
}

// tsk2: Chebyshev-recurrence TS layer; one vb (0..511) per half-block
__device__ __forceinline__ void tsk2_v(int vb,
        const float* __restrict__ tv, const float* __restrict__ rsum,
        const float* __restrict__ P,
        unsigned short* __restrict__ Hh, unsigned short* __restrict__ Hl) {
    const int i   = vb >> 3;
    const int sg  = vb & 7;
    const int w   = (threadIdx.x >> 6) & 3;
    const int ln  = threadIdx.x & 63;       // j
    const int s0  = sg * 256 + w * 64;
    const int idx = i * 64 + ln;
    const float* pp = P + idx * 8;
    const float sf0 = (float)s0;

    float k2c[8], ca[8], cb[8];
#pragma unroll
    for (int g = 0; g < 8; ++g) {
        float pf   = (float)(idx * 8 + g + 2);
        float invp = __builtin_amdgcn_rcpf(pf);
        k2c[g] = 2.0f * __builtin_amdgcn_cosf(invp);     // 2*cos(2*pi/p)
        float q0 = floorf(sf0 * invp);
        float r0 = fmaf(-q0, pf, sf0);
        float f0 = r0 * invp; f0 -= floorf(f0);
        float c0 = __builtin_amdgcn_cosf(f0);
        float sf1 = sf0 + 1.0f;
        float q1 = floorf(sf1 * invp);
        float r1 = fmaf(-q1, pf, sf1);
        float f1 = r1 * invp; f1 -= floorf(f1);
        float c1 = __builtin_amdgcn_cosf(f1);
        float Pv = pp[g];
        ca[g] = Pv * c0;
        cb[g] = Pv * c1;
    }

    const int tb = s0 * 64 + ln;
    float t0c = tv[tb], t1c = tv[131072 + tb];
    float res0 = 0.f, res1 = 0.f;

    for (int st = 0; st < 64; st += 2) {
        float t0n  = tv[tb + (st + 1) * 64];
        float t1n  = tv[131072 + tb + (st + 1) * 64];
        float ws = ((ca[0] + ca[1]) + (ca[2] + ca[3]))
                 + ((ca[4] + ca[5]) + (ca[6] + ca[7]));
#pragma unroll
        for (int g = 0; g < 8; ++g) ca[g] = fmaf(k2c[g], cb[g], -ca[g]);
        float v0 = ws * t0c, v1 = ws * t1c;
#pragma unroll
        for (int m = 1; m < 64; m <<= 1) {
            v0 += __shfl_xor(v0, m, 64);
            v1 += __shfl_xor(v1, m, 64);
        }
        res0 = (ln == st) ? v0 : res0;
        res1 = (ln == st) ? v1 : res1;
        float t0n2 = tv[tb + (st + 2) * 64];
        float t1n2 = tv[131072 + tb + (st + 2) * 64];
        float ws2 = ((cb[0] + cb[1]) + (cb[2] + cb[3]))
                  + ((cb[4] + cb[5]) + (cb[6] + cb[7]));
#pragma unroll
        for (int g = 0; g < 8; ++g) cb[g] = fmaf(k2c[g], ca[g], -cb[g]);
        float v0b = ws2 * t0n, v1b = ws2 * t1n;
#pragma unroll
        for (int m = 1; m < 64; m <<= 1) {
            v0b += __shfl_xor(v0b, m, 64);
            v1b += __shfl_xor(v1b, m, 64);
        }
        res0 = (ln == st + 1) ? v0b : res0;
        res1 = (ln == st + 1) ? v1b : res1;
        t0c = t0n2; t1c = t1n2;
    }

    const int s = s0 + ln;
    {
        float v = res0 + rsum[(size_t)s * 64 + i];
        unsigned short h, l; hilo(v, h, l);
        Hh[(size_t)s * 64 + i] = h; Hl[(size_t)s * 64 + i] = l;
        float v1e = res1 + rsum[(size_t)(SEQ + s) * 64 + i];
        hilo(v1e, h, l);
        Hh[(size_t)(SEQ + s) * 64 + i] = h; Hl[(size_t)(SEQ + s) * 64 + i] = l;
    }
}

// ===========================================================================
// The persistent cooperative megakernel: 256 blocks x 512 threads, 7 syncs.
// wid = bid*2 + half  (512 "virtual workers" of 256 threads each).
// ===========================================================================
__global__ __launch_bounds__(512) void megak(KArgs a) {
    cg::grid_group grid = cg::this_grid();
    const int t    = threadIdx.x;
    const int half = t >> 8;
    const int tid  = t & 255;
    const int bid  = blockIdx.x;
    const int wid  = bid * 2 + half;

    __shared__ __align__(16) unsigned short aH[8192];
    __shared__ __align__(16) unsigned short aL[8192];
    __shared__ __align__(16) unsigned short wH[2][4096];

    float* ws   = a.ws;
    float* C2   = ws;                  // 4 x 524,288
    float* C3r  = ws + 2097152;        // 2,097,152
    float* tbuf = ws + 4194304;        // 262,144
    float* rsum = ws + 4456448;        // 262,144 (must follow tbuf: overrun pad)
    float* A1T  = ws + 4718592;        // 32,768
    float* A3T  = ws + 4751360;        // 32,768
    unsigned short* us = (unsigned short*)(ws + 4784128);
    unsigned short* xh   = us;                  // 2,097,152
    unsigned short* h1h  = us + 2097152;        // 2,097,152
    unsigned short* h1l  = us + 4194304;        // 2,097,152
    unsigned short* W1h  = us + 6291456;        // 262,144
    unsigned short* Wc2h = us + 6553600;        // 65,536
    unsigned short* Wc3h = us + 6619136;        // 65,536
    unsigned short* h2h  = us + 6684672;        // 262,144
    unsigned short* h2l  = us + 6946816;        // 262,144
    unsigned short* C1b  = us + 7208960;        // 2 x 2,097,152
    unsigned short* C3n  = us + 11403264;       // 2,097,152

    // Phase 0: convert + transpose (1344 virtual blocks)
    for (int c = wid; c < 1344; c += 512)
        conv_v(c, tid, a, xh, W1h, Wc2h, Wc3h, A1T, A3T);
    grid.sync();

    // Phase 1: C1b = x @ W1^T (bf16x1, split-K=2, bf16 partials)
    {   // virtual grid (8,32,2): pair (bid) -> bx = 2*(bid&3)+half
        int bn = (bid & 3) * 128 + half * 64;
        int bm = ((bid >> 2) & 31) * 128;
        int bz = bid >> 7;
        gemm512<false, 1>(xh, xh, W1h, nullptr,
                          C1b + (size_t)bz * ROWS * 512,
                          512, 512, 256, bm, bn, bz * 256, aH, aL, wH[half]);
    }
    grid.sync();

    // Phase 2: h1 = RN(LN(C1)) + x
    for (int vb = wid; vb < 1024; vb += 512)
        lnrn_v(vb, C1b, C1b + (size_t)ROWS * 512, a.x, a.g1, a.b1, a.B1, A1T,
               nullptr, h1h, h1l);
    grid.sync();

    // Phase 3: C2 = h1 @ [M2;R2]^T (bf16x2, split-K=4, fp32 partials)
    if (bid < 128) {  // virtual grid (2,32,4): bx = half, by = bid&31, bz = bid>>5
        int bn = half * 64;
        int bm = (bid & 31) * 128;
        int bz = bid >> 5;
        gemm512<true, 0>(h1h, h1l, Wc2h,
                         C2 + (size_t)bz * C2S, nullptr,
                         128, 512, 128, bm, bn, bz * 128, aH, aL, wH[half]);
    }
    grid.sync();

    // Phase 4: sum partials + LN -> t, rsum
    for (int vb = wid; vb < 1024; vb += 512)
        lnt_v(vb, C2, a.g2, a.b2, tbuf, rsum);
    grid.sync();

    // Phase 5: TS Chebyshev recurrence -> h2
    tsk2_v(wid, tbuf, rsum, a.P2, h2h, h2l);
    grid.sync();

    // Phase 6: C3 = h2 @ [W3;R3]^T (bf16x2, mixed out)
    {   // virtual grid (16,32,1): bx = 2*(bid&7)+half
        int bn = (bid & 7) * 128 + half * 64;
        int bm = ((bid >> 3) & 31) * 128;
        gemm512<true, 2>(h2h, h2l, Wc3h, C3r, C3n,
                         1024, 64, 64, bm, bn, 0, aH, aL, wH[half]);
    }
    grid.sync();

    // Phase 7: out = RN(LN(C3n)) + C3r
    for (int vb = wid; vb < 1024; vb += 512)
        lnrn_v(vb, C3n, nullptr, C3r, a.g3, a.b3, a.B3, A3T,
               a.out, nullptr, nullptr);
}

// ===========================================================================
// Fallback path: the original 8-kernel pipeline (verbatim), used only if the
// cooperative launch is rejected (e.g. capture incompatibility).
// ===========================================================================
__global__ __launch_bounds__(256) void convk(
        const float* __restrict__ x,  const float* __restrict__ W1,
        const float* __restrict__ M2, const float* __restrict__ R2,
        const float* __restrict__ W3, const float* __restrict__ R3,
        const float* __restrict__ A1, const float* __restrict__ A3,
        unsigned short* __restrict__ xh,
        unsigned short* __restrict__ W1h,
        unsigned short* __restrict__ C2h,
        unsigned short* __restrict__ C3h,
        float* __restrict__ A1T, float* __restrict__ A3T) {
    int c = blockIdx.x, tid = threadIdx.x;
    if (c < 1216) {
        const float* src; unsigned short* dh; int off;
        if      (c < 1024) { src = x;  dh = xh;          off = c; }
        else if (c < 1152) { src = W1; dh = W1h;         off = c - 1024; }
        else if (c < 1168) { src = M2; dh = C2h;         off = c - 1152; }
        else if (c < 1184) { src = R2; dh = C2h + 32768; off = c - 1168; }
        else if (c < 1200) { src = W3; dh = C3h;         off = c - 1184; }
        else               { src = R3; dh = C3h + 32768; off = c - 1200; }
        int base = off * 2048 + tid * 4;
        cv4h(dh, base,        *(const float4*)(src + base));
        cv4h(dh, base + 1024, *(const float4*)(src + base + 1024));
    } else {
        int gid = (c - 1216) * 256 + tid;
        int i = gid >> 6, j = gid & 63;
        A1T[j * 512 + i] = A1[gid];
        A3T[j * 512 + i] = A3[gid];
    }
}

template<bool ALO, int OM>
__global__ __launch_bounds__(256, 4) void gemm128t(
        const unsigned short* __restrict__ Ah, const unsigned short* __restrict__ Al,
        const unsigned short* __restrict__ Wh,
        float* __restrict__ Cf, unsigned short* __restrict__ Cb,
        int M, int N, int K, int Ks) {
    __shared__ __align__(16) unsigned short aH[8192];
    __shared__ __align__(16) unsigned short aL[ALO ? 8192 : 16];
    __shared__ __align__(16) unsigned short wHs[4096];
    const int tid = threadIdx.x;
    const int wv  = tid >> 6;
    const int ln  = tid & 63;
    const int lm  = ln & 15;
    const int lq  = ln >> 4;
    const int bm  = blockIdx.y * 128;
    const int bn  = blockIdx.x * 64;
    const int k0  = blockIdx.z * Ks;

    f4 acc[2][4] = {};

    for (int kt = 0; kt < Ks; kt += 64) {
        const int kg = k0 + kt;
        __syncthreads();
#pragma unroll
        for (int i = 0; i < 4; ++i) {
            int slot = i * 256 + wv * 64 + ln;
            int row  = slot >> 3;
            int ch   = (slot & 7) ^ (row & 7);
            size_t go = (size_t)(bm + row) * K + kg + ch * 8;
            async16(Ah + go, aH + slot * 8);
            if constexpr (ALO) async16(Al + go, aL + slot * 8);
        }
#pragma unroll
        for (int i = 0; i < 2; ++i) {
            int slot = i * 256 + wv * 64 + ln;
            int row  = slot >> 3;
            int ch   = (slot & 7) ^ (row & 7);
            size_t go = (size_t)(bn + row) * K + kg + ch * 8;
            async16(Wh + go, wHs + slot * 8);
        }
        __syncthreads();

#pragma unroll
        for (int kk = 0; kk < 2; ++kk) {
            const int ck = kk * 4 + lq;
            bf8 a_h[2], a_l[2], b_h[4];
#pragma unroll
            for (int t = 0; t < 2; ++t) {
                int r = wv * 32 + t * 16 + lm;
                a_h[t] = *(const bf8*)(aH + r * 64 + ((ck ^ (r & 7)) * 8));
                if constexpr (ALO)
                    a_l[t] = *(const bf8*)(aL + r * 64 + ((ck ^ (r & 7)) * 8));
            }
#pragma unroll
            for (int u = 0; u < 4; ++u) {
                int rb = u * 16 + lm;
                b_h[u] = *(const bf8*)(wHs + rb * 64 + ((ck ^ (rb & 7)) * 8));
            }
#pragma unroll
            for (int t = 0; t < 2; ++t)
#pragma unroll
                for (int u = 0; u < 4; ++u) {
                    acc[t][u] = __builtin_amdgcn_mfma_f32_16x16x32_bf16(a_h[t], b_h[u], acc[t][u], 0, 0, 0);
                    if constexpr (ALO)
                        acc[t][u] = __builtin_amdgcn_mfma_f32_16x16x32_bf16(a_l[t], b_h[u], acc[t][u], 0, 0, 0);
                }
        }
    }

#pragma unroll
    for (int t = 0; t < 2; ++t)
#pragma unroll
        for (int u = 0; u < 4; ++u) {
            int row = bm + wv * 32 + t * 16 + lq * 4;
            int col = bn + u * 16 + lm;
#pragma unroll
            for (int r = 0; r < 4; ++r) {
                float v = acc[t][u][r];
                if constexpr (OM == 0) {
                    Cf[(size_t)blockIdx.z * M * N + (size_t)(row + r) * N + col] = v;
                } else if constexpr (OM == 1) {
                    Cb[(size_t)blockIdx.z * M * N + (size_t)(row + r) * N + col] = f2bf(v);
                } else {
                    if (col < 512) Cb[(size_t)(row + r) * 512 + col] = f2bf(v);
                    else           Cf[(size_t)(row + r) * 512 + col - 512] = v;
                }
            }
        }
}

__global__ __launch_bounds__(256) void lnrn(
        const unsigned short* __restrict__ Yb0,
        const unsigned short* __restrict__ Yb1,
        const float* __restrict__ RES,
        const float* __restrict__ g, const float* __restrict__ be,
        const float* __restrict__ Bb, const float* __restrict__ AaT,
        float* __restrict__ outf,
        unsigned short* __restrict__ outh, unsigned short* __restrict__ outl) {
    // delegate to the device body (same semantics: row = blockIdx.x*4 + wave)
    lnrn_v(blockIdx.x, Yb0, Yb1, RES, g, be, Bb, AaT, outf, outh, outl);
}

__global__ __launch_bounds__(256) void lnt(
        const float* __restrict__ C2, const float* __restrict__ g2,
        const float* __restrict__ b2,
        float* __restrict__ t, float* __restrict__ rsum) {
    lnt_v(blockIdx.x, C2, g2, b2, t, rsum);
}

__global__ __launch_bounds__(256) void tsk2(
        const float* __restrict__ t, const float* __restrict__ rsum,
        const float* __restrict__ P,
        unsigned short* __restrict__ Hh, unsigned short* __restrict__ Hl) {
    tsk2_v(blockIdx.x, t, rsum, P, Hh, Hl);
}

// ---------------------------------------------------------------------------
extern "C" void kernel_launch(void* const* d_in, const int* in_sizes, int n_in,
                              void* d_out, int out_size, void* d_ws, size_t ws_size,
                              hipStream_t stream) {
    (void)in_sizes; (void)n_in; (void)out_size; (void)ws_size;
    KArgs a;
    a.x  = (const float*)d_in[0];
    a.W1 = (const float*)d_in[1];
    a.g1 = (const float*)d_in[2];
    a.b1 = (const float*)d_in[3];
    a.A1 = (const float*)d_in[4];
    a.B1 = (const float*)d_in[5];
    a.M2 = (const float*)d_in[6];
    a.g2 = (const float*)d_in[7];
    a.b2 = (const float*)d_in[8];
    a.P2 = (const float*)d_in[9];
    a.R2 = (const float*)d_in[10];
    a.W3 = (const float*)d_in[11];
    a.g3 = (const float*)d_in[12];
    a.b3 = (const float*)d_in[13];
    a.A3 = (const float*)d_in[14];
    a.B3 = (const float*)d_in[15];
    a.R3 = (const float*)d_in[16];
    a.out = (float*)d_out;
    a.ws  = (float*)d_ws;

    void* kargs[] = { (void*)&a };
    hipError_t e = hipLaunchCooperativeKernel((const void*)megak,
                                              dim3(256), dim3(512),
                                              kargs, 0, stream);
    if (e == hipSuccess) return;

    // -------- fallback: original 8-kernel pipeline --------
    float* ws = (float*)d_ws;
    float* C2   = ws;
    float* C3r  = ws + 2097152;
    float* t    = ws + 4194304;
    float* rsum = ws + 4456448;
    float* A1T  = ws + 4718592;
    float* A3T  = ws + 4751360;
    unsigned short* us = (unsigned short*)(ws + 4784128);
    unsigned short* xh   = us;
    unsigned short* h1h  = us + 2097152;
    unsigned short* h1l  = us + 4194304;
    unsigned short* W1h  = us + 6291456;
    unsigned short* Wc2h = us + 6553600;
    unsigned short* Wc3h = us + 6619136;
    unsigned short* h2h  = us + 6684672;
    unsigned short* h2l  = us + 6946816;
    unsigned short* C1b  = us + 7208960;
    unsigned short* C3n  = us + 11403264;

    dim3 blk(256);
    convk<<<1344, blk, 0, stream>>>(a.x, a.W1, a.M2, a.R2, a.W3, a.R3, a.A1, a.A3,
                                    xh, W1h, Wc2h, Wc3h, A1T, A3T);
    gemm128t<false, 1><<<dim3(8, 32, 2), blk, 0, stream>>>(
        xh, xh, W1h, nullptr, C1b, ROWS, 512, 512, 256);
    lnrn<<<1024, blk, 0, stream>>>(C1b, C1b + (size_t)ROWS * 512, a.x,
                                   a.g1, a.b1, a.B1, A1T, nullptr, h1h, h1l);
    gemm128t<true, 0><<<dim3(2, 32, 4), blk, 0, stream>>>(
        h1h, h1l, Wc2h, C2, nullptr, ROWS, 128, 512, 128);
    lnt<<<1024, blk, 0, stream>>>(C2, a.g2, a.b2, t, rsum);
    tsk2<<<512, blk, 0, stream>>>(t, rsum, a.P2, h2h, h2l);
    gemm128t<true, 2><<<dim3(16, 32, 1), blk, 0, stream>>>(
        h2h, h2l, Wc3h, C3r, C3n, ROWS, 1024, 64, 64);
    lnrn<<<1024, blk, 0, stream>>>(C3n, nullptr, C3r, a.g3, a.b3, a.B3, A3T,
                                   (float*)d_out, nullptr, nullptr);
}

// Round 3
// 146.708 us; speedup vs baseline: 2.7173x; 2.7173x over previous
//
#include <hip/hip_runtime.h>
#include <math.h>

#define SEQ  2048
#define ROWS 4096
#define D0   512
#define D1   64
#define C2S  524288

typedef short bf8 __attribute__((ext_vector_type(8)));   // 8 bf16 = 4 VGPRs
typedef float f4  __attribute__((ext_vector_type(4)));   // MFMA acc

// fp32 -> bf16 (RNE) and hi/lo split
__device__ __forceinline__ unsigned short f2bf(float f) {
    unsigned u = __float_as_uint(f);
    return (unsigned short)((u + 0x7fffu + ((u >> 16) & 1u)) >> 16);
}
__device__ __forceinline__ float bf2f(unsigned short u) {
    return __uint_as_float((unsigned)u << 16);
}
__device__ __forceinline__ void hilo(float f, unsigned short& h, unsigned short& l) {
    h = f2bf(f);
    float fh = bf2f(h);
    l = f2bf(f - fh);
}
__device__ __forceinline__ void cv4h(unsigned short* dh, int idx, float4 v) {
    ushort4 hv;
    hv.x = f2bf(v.x); hv.y = f2bf(v.y); hv.z = f2bf(v.z); hv.w = f2bf(v.w);
    *(ushort4*)(dh + idx) = hv;
}

// async global->LDS 16B (dest = wave-uniform base + lane*16)
__device__ __forceinline__ void async16(const void* g, void* l) {
    __builtin_amdgcn_global_load_lds(
        (const __attribute__((address_space(1))) unsigned int*)g,
        (__attribute__((address_space(3))) unsigned int*)l, 16, 0, 0);
}

// ---------------------------------------------------------------------------
// convk: x -> xh+xl (hi/lo); weights -> bf16 hi; A3 transpose;
// G2y[jm,j] = sum_c A1[c,jm]*M2[j,c]; G2r[jm,i] = sum_c A1[c,jm]*R2[i,c].
// (rank-1 folding: layer-2 sees h1 = p*A1col(jm) + x, so
//  C2 = x@[M2;R2]^T + p*G  -- G is 64x128, computed here in fp32.)
// ---------------------------------------------------------------------------
__global__ __launch_bounds__(256) void convk(
        const float* __restrict__ x,  const float* __restrict__ W1,
        const float* __restrict__ M2, const float* __restrict__ R2,
        const float* __restrict__ W3, const float* __restrict__ R3,
        const float* __restrict__ A1, const float* __restrict__ A3,
        unsigned short* __restrict__ xh, unsigned short* __restrict__ xl,
        unsigned short* __restrict__ W1h,    // head of 640-row Wbig region
        unsigned short* __restrict__ C2h,    // rows 512..639 of Wbig (M2;R2)
        unsigned short* __restrict__ C3h,
        float* __restrict__ A3T,
        float* __restrict__ G2y, float* __restrict__ G2r) {
    __shared__ float sh[4][64];
    int c = blockIdx.x, tid = threadIdx.x;
    if (c < 1024) {
        int base = c * 2048 + tid * 4;
        float4 v0 = *(const float4*)(x + base);
        float4 v1 = *(const float4*)(x + base + 1024);
        ushort4 h, l;
        hilo(v0.x, h.x, l.x); hilo(v0.y, h.y, l.y);
        hilo(v0.z, h.z, l.z); hilo(v0.w, h.w, l.w);
        *(ushort4*)(xh + base) = h; *(ushort4*)(xl + base) = l;
        hilo(v1.x, h.x, l.x); hilo(v1.y, h.y, l.y);
        hilo(v1.z, h.z, l.z); hilo(v1.w, h.w, l.w);
        *(ushort4*)(xh + base + 1024) = h; *(ushort4*)(xl + base + 1024) = l;
    } else if (c < 1216) {
        const float* src; unsigned short* dh; int off;
        if      (c < 1152) { src = W1; dh = W1h;         off = c - 1024; }
        else if (c < 1168) { src = M2; dh = C2h;         off = c - 1152; }
        else if (c < 1184) { src = R2; dh = C2h + 32768; off = c - 1168; }
        else if (c < 1200) { src = W3; dh = C3h;         off = c - 1184; }
        else               { src = R3; dh = C3h + 32768; off = c - 1200; }
        int base = off * 2048 + tid * 4;
        cv4h(dh, base,        *(const float4*)(src + base));
        cv4h(dh, base + 1024, *(const float4*)(src + base + 1024));
    } else if (c < 1344) {
        int gid = (c - 1216) * 256 + tid;     // 0..32767
        int i = gid >> 6, j = gid & 63;       // A3 (512 x 64)
        A3T[j * 512 + i] = A3[gid];
    } else {
        // G blocks: 1344..1407 -> G2y rows j; 1408..1471 -> G2r rows i
        int jrow = (c - 1344) & 63;
        const float* wv = (c < 1408) ? (M2 + jrow * 512) : (R2 + jrow * 512);
        float* G = (c < 1408) ? G2y : G2r;
        int jm = tid & 63, q = tid >> 6;
        const float* ap = A1 + (q * 128) * 64 + jm;
        const float* wp = wv + q * 128;
        float acc = 0.f;
        for (int cc = 0; cc < 128; ++cc)
            acc = fmaf(ap[cc * 64], wp[cc], acc);
        sh[q][jm] = acc;
        __syncthreads();
        if (tid < 64)
            G[tid * 64 + jrow] = (sh[0][tid] + sh[1][tid]) + (sh[2][tid] + sh[3][tid]);
    }
}

// ---------------------------------------------------------------------------
// MFMA GEMM, 128(M) x 64(N) tile, BK=64, 256 thr = 4 waves.
// AMODE: 0 = hi only; 1 = hi+lo always; 2 = hi+lo iff bn>=512 (Wbig's LN cols).
// OM: 2 = mixed (bn<512 -> bf16 at ld 512; bn>=512 -> fp32 at ld 512);
//     3 = split-K partials, col<512 bf16 at ld 512, col>=512 fp32 at ld 128.
// XOR-swizzled LDS (swizzle on global source idx; dest stays wave-uniform).
// ---------------------------------------------------------------------------
template<int AMODE, int OM>
__global__ __launch_bounds__(256, 4) void gemm128t(
        const unsigned short* __restrict__ Ah, const unsigned short* __restrict__ Al,
        const unsigned short* __restrict__ Wh,
        float* __restrict__ Cf, unsigned short* __restrict__ Cb,
        int N, int K, int Ks) {
    __shared__ __align__(16) unsigned short aH[8192];
    __shared__ __align__(16) unsigned short aL[AMODE ? 8192 : 16];
    __shared__ __align__(16) unsigned short wHs[4096];
    const int tid = threadIdx.x;
    const int wv  = tid >> 6;
    const int ln  = tid & 63;
    const int lm  = ln & 15;
    const int lq  = ln >> 4;
    const int bm  = blockIdx.y * 128;
    const int bn  = blockIdx.x * 64;
    const int k0  = blockIdx.z * Ks;
    const bool alo = (AMODE == 1) || (AMODE == 2 && bn >= 512);

    f4 acc[2][4] = {};

    for (int kt = 0; kt < Ks; kt += 64) {
        const int kg = k0 + kt;
        __syncthreads();
#pragma unroll
        for (int i = 0; i < 4; ++i) {
            int slot = i * 256 + wv * 64 + ln;
            int row  = slot >> 3;
            int ch   = (slot & 7) ^ (row & 7);
            size_t go = (size_t)(bm + row) * K + kg + ch * 8;
            async16(Ah + go, aH + slot * 8);
            if (alo) async16(Al + go, aL + slot * 8);
        }
#pragma unroll
        for (int i = 0; i < 2; ++i) {
            int slot = i * 256 + wv * 64 + ln;
            int row  = slot >> 3;
            int ch   = (slot & 7) ^ (row & 7);
            size_t go = (size_t)(bn + row) * K + kg + ch * 8;
            async16(Wh + go, wHs + slot * 8);
        }
        __syncthreads();

#pragma unroll
        for (int kk = 0; kk < 2; ++kk) {
            const int ck = kk * 4 + lq;          // 16B chunk index in k
            bf8 a_h[2], a_l[2], b_h[4];
#pragma unroll
            for (int t = 0; t < 2; ++t) {
                int r = wv * 32 + t * 16 + lm;
                a_h[t] = *(const bf8*)(aH + r * 64 + ((ck ^ (r & 7)) * 8));
                if (alo)
                    a_l[t] = *(const bf8*)(aL + r * 64 + ((ck ^ (r & 7)) * 8));
            }
#pragma unroll
            for (int u = 0; u < 4; ++u) {
                int rb = u * 16 + lm;
                b_h[u] = *(const bf8*)(wHs + rb * 64 + ((ck ^ (rb & 7)) * 8));
            }
#pragma unroll
            for (int t = 0; t < 2; ++t)
#pragma unroll
                for (int u = 0; u < 4; ++u) {
                    acc[t][u] = __builtin_amdgcn_mfma_f32_16x16x32_bf16(a_h[t], b_h[u], acc[t][u], 0, 0, 0);
                    if (alo)
                        acc[t][u] = __builtin_amdgcn_mfma_f32_16x16x32_bf16(a_l[t], b_h[u], acc[t][u], 0, 0, 0);
                }
        }
    }

    // C/D layout (verified): col = lane&15, row = quad*4 + reg
#pragma unroll
    for (int t = 0; t < 2; ++t)
#pragma unroll
        for (int u = 0; u < 4; ++u) {
            int row = bm + wv * 32 + t * 16 + lq * 4;
            int col = bn + u * 16 + lm;
#pragma unroll
            for (int r = 0; r < 4; ++r) {
                float v = acc[t][u][r];
                if constexpr (OM == 2) {
                    if (col < 512) Cb[(size_t)(row + r) * 512 + col] = f2bf(v);
                    else           Cf[(size_t)(row + r) * 512 + col - 512] = v;
                } else { // OM == 3: split-K partials
                    if (col < 512)
                        Cb[(size_t)blockIdx.z * ROWS * 512 + (size_t)(row + r) * 512 + col] = f2bf(v);
                    else
                        Cf[(size_t)blockIdx.z * ROWS * 128 + (size_t)(row + r) * 128 + (col - 512)] = v;
                }
            }
        }
}

// ---------------------------------------------------------------------------
// ptk: one row per wave. From C1 partials (bf16 x2): row reduces ->
// p = rstd*(S1 - mean*SU) + SBB  (== sum_c n*Bv with n = (y-mean)rstd*g+b).
// Then t = LN64( C2y + p*G2y[jm] ) and rsum = C2r + p*G2r[jm].
// Replaces the old lnrn1 (h1 materialization) + lnt kernels.
// ---------------------------------------------------------------------------
__global__ __launch_bounds__(256) void ptk(
        const unsigned short* __restrict__ C1b,   // 2 planes ROWS x 512 bf16
        const float* __restrict__ C2,             // 2 planes ROWS x 128 fp32
        const float* __restrict__ B1,
        const float* __restrict__ g1, const float* __restrict__ b1,
        const float* __restrict__ g2, const float* __restrict__ b2,
        const float* __restrict__ G2y, const float* __restrict__ G2r,
        float* __restrict__ t, float* __restrict__ rsum) {
    const int row = blockIdx.x * 4 + (threadIdx.x >> 6);
    const int l = threadIdx.x & 63;
    const int c = l * 8;
    const int jm = row & 63;
    const size_t rb0 = (size_t)row * 512 + c;
    ushort4 ua = *(const ushort4*)(C1b + rb0);
    ushort4 ub = *(const ushort4*)(C1b + rb0 + 4);
    ushort4 va = *(const ushort4*)(C1b + (size_t)ROWS * 512 + rb0);
    ushort4 vb = *(const ushort4*)(C1b + (size_t)ROWS * 512 + rb0 + 4);
    float y[8];
    y[0] = bf2f(ua.x) + bf2f(va.x); y[1] = bf2f(ua.y) + bf2f(va.y);
    y[2] = bf2f(ua.z) + bf2f(va.z); y[3] = bf2f(ua.w) + bf2f(va.w);
    y[4] = bf2f(ub.x) + bf2f(vb.x); y[5] = bf2f(ub.y) + bf2f(vb.y);
    y[6] = bf2f(ub.z) + bf2f(vb.z); y[7] = bf2f(ub.w) + bf2f(vb.w);
    float4 B0  = *(const float4*)(B1 + jm * 512 + c);
    float4 B1q = *(const float4*)(B1 + jm * 512 + c + 4);
    float4 gg0 = *(const float4*)(g1 + c), gg1 = *(const float4*)(g1 + c + 4);
    float4 bb0 = *(const float4*)(b1 + c), bb1 = *(const float4*)(b1 + c + 4);
    float Bv[8] = {B0.x, B0.y, B0.z, B0.w, B1q.x, B1q.y, B1q.z, B1q.w};
    float gv[8] = {gg0.x, gg0.y, gg0.z, gg0.w, gg1.x, gg1.y, gg1.z, gg1.w};
    float bv[8] = {bb0.x, bb0.y, bb0.z, bb0.w, bb1.x, bb1.y, bb1.z, bb1.w};
    float sum = 0.f, ssq = 0.f, S1 = 0.f, SU = 0.f, SBB = 0.f;
#pragma unroll
    for (int i = 0; i < 8; ++i) {
        float u = gv[i] * Bv[i];
        sum += y[i];
        ssq = fmaf(y[i], y[i], ssq);
        S1  = fmaf(y[i], u, S1);
        SU  += u;
        SBB = fmaf(bv[i], Bv[i], SBB);
    }
#pragma unroll
    for (int m = 1; m < 64; m <<= 1) {
        sum += __shfl_xor(sum, m, 64);
        ssq += __shfl_xor(ssq, m, 64);
        S1  += __shfl_xor(S1, m, 64);
        SU  += __shfl_xor(SU, m, 64);
        SBB += __shfl_xor(SBB, m, 64);
    }
    float mean = sum * (1.0f / 512.0f);
    float var  = ssq * (1.0f / 512.0f) - mean * mean;
    float rstd = rsqrtf(var + 1e-5f);
    float p = rstd * (S1 - mean * SU) + SBB;

    const size_t rb = (size_t)row * 128;
    float z  = C2[rb + l]      + C2[C2S + rb + l];
    float zr = C2[rb + 64 + l] + C2[C2S + rb + 64 + l];
    float v  = z  + p * G2y[jm * 64 + l];
    float rv = zr + p * G2r[jm * 64 + l];
    float s2 = v, q2 = v * v;
#pragma unroll
    for (int m = 1; m < 64; m <<= 1) {
        s2 += __shfl_xor(s2, m, 64);
        q2 += __shfl_xor(q2, m, 64);
    }
    float mean2 = s2 * (1.0f / 64.0f);
    float var2  = q2 * (1.0f / 64.0f) - mean2 * mean2;
    float rstd2 = rsqrtf(var2 + 1e-5f);
    t[row * 64 + l]    = (v - mean2) * rstd2 * g2[l] + b2[l];
    rsum[row * 64 + l] = rv;
}

// ---------------------------------------------------------------------------
// LN + rank-1 RN epilogue (final layer), one row per wave.
// ---------------------------------------------------------------------------
__global__ __launch_bounds__(256) void lnrn(
        const unsigned short* __restrict__ Yb0,
        const float* __restrict__ RES,
        const float* __restrict__ g, const float* __restrict__ be,
        const float* __restrict__ Bb, const float* __restrict__ AaT,
        float* __restrict__ outf) {
    const int row = blockIdx.x * 4 + (threadIdx.x >> 6);
    const int l = threadIdx.x & 63;
    const int c = l * 8;
    ushort4 ua = *(const ushort4*)(Yb0 + (size_t)row * D0 + c);
    ushort4 ub = *(const ushort4*)(Yb0 + (size_t)row * D0 + c + 4);
    float4 y0, y1;
    y0.x = bf2f(ua.x); y0.y = bf2f(ua.y); y0.z = bf2f(ua.z); y0.w = bf2f(ua.w);
    y1.x = bf2f(ub.x); y1.y = bf2f(ub.y); y1.z = bf2f(ub.z); y1.w = bf2f(ub.w);
    float sum = y0.x + y0.y + y0.z + y0.w + y1.x + y1.y + y1.z + y1.w;
    float ssq = y0.x*y0.x + y0.y*y0.y + y0.z*y0.z + y0.w*y0.w
              + y1.x*y1.x + y1.y*y1.y + y1.z*y1.z + y1.w*y1.w;
#pragma unroll
    for (int m = 1; m < 64; m <<= 1) {
        sum += __shfl_xor(sum, m, 64);
        ssq += __shfl_xor(ssq, m, 64);
    }
    float mean = sum * (1.0f / 512.0f);
    float var  = ssq * (1.0f / 512.0f) - mean * mean;
    float rstd = rsqrtf(var + 1e-5f);
    float4 g0 = *(const float4*)(g + c),  g1v = *(const float4*)(g + c + 4);
    float4 e0 = *(const float4*)(be + c), e1  = *(const float4*)(be + c + 4);
    float4 n0, n1;
    n0.x = (y0.x - mean) * rstd * g0.x  + e0.x;
    n0.y = (y0.y - mean) * rstd * g0.y  + e0.y;
    n0.z = (y0.z - mean) * rstd * g0.z  + e0.z;
    n0.w = (y0.w - mean) * rstd * g0.w  + e0.w;
    n1.x = (y1.x - mean) * rstd * g1v.x + e1.x;
    n1.y = (y1.y - mean) * rstd * g1v.y + e1.y;
    n1.z = (y1.z - mean) * rstd * g1v.z + e1.z;
    n1.w = (y1.w - mean) * rstd * g1v.w + e1.w;
    const int jm = row & 63;
    const float* bb = Bb + jm * D0 + c;
    float4 b0 = *(const float4*)bb, b1v = *(const float4*)(bb + 4);
    float p = n0.x*b0.x + n0.y*b0.y + n0.z*b0.z + n0.w*b0.w
            + n1.x*b1v.x + n1.y*b1v.y + n1.z*b1v.z + n1.w*b1v.w;
#pragma unroll
    for (int m = 1; m < 64; m <<= 1) p += __shfl_xor(p, m, 64);
    const float* av = AaT + jm * D0 + c;
    float4 a0 = *(const float4*)av, a1 = *(const float4*)(av + 4);
    const float* rs = RES + (size_t)row * D0 + c;
    float4 r0 = *(const float4*)rs, r1 = *(const float4*)(rs + 4);
    float4 v0, v1;
    v0.x = p*a0.x + r0.x; v0.y = p*a0.y + r0.y; v0.z = p*a0.z + r0.z; v0.w = p*a0.w + r0.w;
    v1.x = p*a1.x + r1.x; v1.y = p*a1.y + r1.y; v1.z = p*a1.z + r1.z; v1.w = p*a1.w + r1.w;
    *(float4*)(outf + (size_t)row * D0 + c)     = v0;
    *(float4*)(outf + (size_t)row * D0 + c + 4) = v1;
}

// ---------------------------------------------------------------------------
// tsk2: Chebyshev-recurrence TS layer (verified R5/R6 of prior session).
// ---------------------------------------------------------------------------
__global__ __launch_bounds__(256) void tsk2(
        const float* __restrict__ t, const float* __restrict__ rsum,
        const float* __restrict__ P,
        unsigned short* __restrict__ Hh, unsigned short* __restrict__ Hl) {
    const int bid = blockIdx.x;
    const int i   = bid >> 3;
    const int sg  = bid & 7;
    const int w   = threadIdx.x >> 6;
    const int ln  = threadIdx.x & 63;       // j
    const int s0  = sg * 256 + w * 64;
    const int idx = i * 64 + ln;
    const float* pp = P + idx * 8;
    const float sf0 = (float)s0;

    float k2c[8], ca[8], cb[8];
#pragma unroll
    for (int g = 0; g < 8; ++g) {
        float pf   = (float)(idx * 8 + g + 2);
        float invp = __builtin_amdgcn_rcpf(pf);
        k2c[g] = 2.0f * __builtin_amdgcn_cosf(invp);     // 2*cos(2*pi/p)
        float q0 = floorf(sf0 * invp);
        float r0 = fmaf(-q0, pf, sf0);
        float f0 = r0 * invp; f0 -= floorf(f0);
        float c0 = __builtin_amdgcn_cosf(f0);
        float sf1 = sf0 + 1.0f;
        float q1 = floorf(sf1 * invp);
        float r1 = fmaf(-q1, pf, sf1);
        float f1 = r1 * invp; f1 -= floorf(f1);
        float c1 = __builtin_amdgcn_cosf(f1);
        float Pv = pp[g];
        ca[g] = Pv * c0;
        cb[g] = Pv * c1;
    }

    const int tb = s0 * 64 + ln;
    float t0c = t[tb], t1c = t[131072 + tb];
    float res0 = 0.f, res1 = 0.f;

    for (int st = 0; st < 64; st += 2) {
        float t0n  = t[tb + (st + 1) * 64];
        float t1n  = t[131072 + tb + (st + 1) * 64];
        float ws = ((ca[0] + ca[1]) + (ca[2] + ca[3]))
                 + ((ca[4] + ca[5]) + (ca[6] + ca[7]));
#pragma unroll
        for (int g = 0; g < 8; ++g) ca[g] = fmaf(k2c[g], cb[g], -ca[g]);
        float v0 = ws * t0c, v1 = ws * t1c;
#pragma unroll
        for (int m = 1; m < 64; m <<= 1) {
            v0 += __shfl_xor(v0, m, 64);
            v1 += __shfl_xor(v1, m, 64);
        }
        res0 = (ln == st) ? v0 : res0;
        res1 = (ln == st) ? v1 : res1;
        float t0n2 = t[tb + (st + 2) * 64];
        float t1n2 = t[131072 + tb + (st + 2) * 64];
        float ws2 = ((cb[0] + cb[1]) + (cb[2] + cb[3]))
                  + ((cb[4] + cb[5]) + (cb[6] + cb[7]));
#pragma unroll
        for (int g = 0; g < 8; ++g) cb[g] = fmaf(k2c[g], ca[g], -cb[g]);
        float v0b = ws2 * t0n, v1b = ws2 * t1n;
#pragma unroll
        for (int m = 1; m < 64; m <<= 1) {
            v0b += __shfl_xor(v0b, m, 64);
            v1b += __shfl_xor(v1b, m, 64);
        }
        res0 = (ln == st + 1) ? v0b : res0;
        res1 = (ln == st + 1) ? v1b : res1;
        t0c = t0n2; t1c = t1n2;
    }

    const int s = s0 + ln;
    {
        float v = res0 + rsum[(size_t)s * 64 + i];
        unsigned short h, l; hilo(v, h, l);
        Hh[(size_t)s * 64 + i] = h; Hl[(size_t)s * 64 + i] = l;
        float v1e = res1 + rsum[(size_t)(SEQ + s) * 64 + i];
        hilo(v1e, h, l);
        Hh[(size_t)(SEQ + s) * 64 + i] = h; Hl[(size_t)(SEQ + s) * 64 + i] = l;
    }
}

// ---------------------------------------------------------------------------
extern "C" void kernel_launch(void* const* d_in, const int* in_sizes, int n_in,
                              void* d_out, int out_size, void* d_ws, size_t ws_size,
                              hipStream_t stream) {
    (void)in_sizes; (void)n_in; (void)out_size; (void)ws_size;
    const float* x  = (const float*)d_in[0];
    const float* W1 = (const float*)d_in[1];
    const float* g1 = (const float*)d_in[2];
    const float* b1 = (const float*)d_in[3];
    const float* A1 = (const float*)d_in[4];
    const float* B1 = (const float*)d_in[5];
    const float* M2 = (const float*)d_in[6];
    const float* g2 = (const float*)d_in[7];
    const float* b2 = (const float*)d_in[8];
    const float* P2 = (const float*)d_in[9];
    const float* R2 = (const float*)d_in[10];
    const float* W3 = (const float*)d_in[11];
    const float* g3 = (const float*)d_in[12];
    const float* b3 = (const float*)d_in[13];
    const float* A3 = (const float*)d_in[14];
    const float* B3 = (const float*)d_in[15];
    const float* R3 = (const float*)d_in[16];

    float* ws = (float*)d_ws;
    float* C2   = ws;                  // 2 x 524,288 fp32 partials (y|res, ld 128)
    float* C3r  = ws + 2097152;        // 2,097,152 (4096 x 512 fp32 residual)
    float* t    = ws + 4194304;        // 262,144
    float* rsum = ws + 4456448;        // 262,144 (must follow t: overrun pad)
    float* G2y  = ws + 4718592;        // 4,096 (old A1T slot reused)
    float* G2r  = ws + 4722688;        // 4,096
    float* A3T  = ws + 4751360;        // 32,768
    unsigned short* us = (unsigned short*)(ws + 4784128);
    unsigned short* xh   = us;                  // 2,097,152
    unsigned short* xl   = us + 2097152;        // 2,097,152 (old h1h slot)
    unsigned short* W1h  = us + 6291456;        // 262,144 (rows 0..511 of Wbig)
    unsigned short* Wc2h = us + 6553600;        // 65,536  (rows 512..639 of Wbig)
    unsigned short* Wc3h = us + 6619136;        // 65,536 (1024 x 64)
    unsigned short* h2h  = us + 6684672;        // 262,144
    unsigned short* h2l  = us + 6946816;        // 262,144
    unsigned short* C1b  = us + 7208960;        // 2 x 2,097,152 (bf16 partials)
    unsigned short* C3n  = us + 11403264;       // 2,097,152 (4096 x 512 bf16)

    dim3 blk(256);

    // 0) convert x (hi+lo) + weights (hi) + A3 transpose + G2y/G2r
    convk<<<1472, blk, 0, stream>>>(x, W1, M2, R2, W3, R3, A1, A3,
                                    xh, xl, W1h, Wc2h, Wc3h, A3T, G2y, G2r);

    // 1) merged GEMM: [C1 | C2y | C2r] = x @ [W1; M2; R2]^T  (N=640, split-K=2)
    //    A-lo plane applied only to cols >= 512 (LN-direct path).
    gemm128t<2, 3><<<dim3(10, 32, 2), blk, 0, stream>>>(
        xh, xl, W1h, C2, C1b, 640, 512, 256);

    // 2) p from C1 row-reduces; t = LN64(C2y + p*G2y); rsum = C2r + p*G2r
    ptk<<<1024, blk, 0, stream>>>(C1b, C2, B1, g1, b1, g2, b2, G2y, G2r, t, rsum);

    // 3) TS Chebyshev recurrence -> h2 (hi/lo)
    tsk2<<<512, blk, 0, stream>>>(t, rsum, P2, h2h, h2l);

    // 4) C3 = h2 @ [W3;R3]^T (bf16x2, mixed out: LN-half bf16, residual fp32)
    gemm128t<1, 2><<<dim3(16, 32, 1), blk, 0, stream>>>(
        h2h, h2l, Wc3h, C3r, C3n, 1024, 64, 64);

    // 5) out = RN(LN(C3n)) + C3r
    lnrn<<<1024, blk, 0, stream>>>(C3n, C3r, g3, b3, B3, A3T, (float*)d_out);
}

// Round 4
// 143.689 us; speedup vs baseline: 2.7744x; 1.0210x over previous
//
#include <hip/hip_runtime.h>
#include <math.h>

#define SEQ  2048
#define ROWS 4096
#define D0   512
#define D1   64
#define C2S  524288

typedef short bf8 __attribute__((ext_vector_type(8)));   // 8 bf16 = 4 VGPRs
typedef float f4  __attribute__((ext_vector_type(4)));   // MFMA acc

// fp32 -> bf16 (RNE) and hi/lo split
__device__ __forceinline__ unsigned short f2bf(float f) {
    unsigned u = __float_as_uint(f);
    return (unsigned short)((u + 0x7fffu + ((u >> 16) & 1u)) >> 16);
}
__device__ __forceinline__ float bf2f(unsigned short u) {
    return __uint_as_float((unsigned)u << 16);
}
__device__ __forceinline__ void hilo(float f, unsigned short& h, unsigned short& l) {
    h = f2bf(f);
    float fh = bf2f(h);
    l = f2bf(f - fh);
}
__device__ __forceinline__ void cv4h(unsigned short* dh, int idx, float4 v) {
    ushort4 hv;
    hv.x = f2bf(v.x); hv.y = f2bf(v.y); hv.z = f2bf(v.z); hv.w = f2bf(v.w);
    *(ushort4*)(dh + idx) = hv;
}

// async global->LDS 16B (dest = wave-uniform base + lane*16)
__device__ __forceinline__ void async16(const void* g, void* l) {
    __builtin_amdgcn_global_load_lds(
        (const __attribute__((address_space(1))) unsigned int*)g,
        (__attribute__((address_space(3))) unsigned int*)l, 16, 0, 0);
}

// ---------------------------------------------------------------------------
// convk: x -> xh+xl (hi/lo); weights -> bf16 hi; A3 transpose;
// G2y[jm,j] = sum_c A1[c,jm]*M2[j,c]; G2r[jm,i] = sum_c A1[c,jm]*R2[i,c].
// (rank-1 folding: layer-2 sees h1 = p*A1col(jm) + x, so
//  C2 = x@[M2;R2]^T + p*G  -- G is 64x128, computed here in fp32.)
// ---------------------------------------------------------------------------
__global__ __launch_bounds__(256) void convk(
        const float* __restrict__ x,  const float* __restrict__ W1,
        const float* __restrict__ M2, const float* __restrict__ R2,
        const float* __restrict__ W3, const float* __restrict__ R3,
        const float* __restrict__ A1, const float* __restrict__ A3,
        unsigned short* __restrict__ xh, unsigned short* __restrict__ xl,
        unsigned short* __restrict__ W1h,    // head of 640-row Wbig region
        unsigned short* __restrict__ C2h,    // rows 512..639 of Wbig (M2;R2)
        unsigned short* __restrict__ C3h,
        float* __restrict__ A3T,
        float* __restrict__ G2y, float* __restrict__ G2r) {
    __shared__ float sh[4][64];
    int c = blockIdx.x, tid = threadIdx.x;
    if (c < 1024) {
        int base = c * 2048 + tid * 4;
        float4 v0 = *(const float4*)(x + base);
        float4 v1 = *(const float4*)(x + base + 1024);
        ushort4 h, l;
        hilo(v0.x, h.x, l.x); hilo(v0.y, h.y, l.y);
        hilo(v0.z, h.z, l.z); hilo(v0.w, h.w, l.w);
        *(ushort4*)(xh + base) = h; *(ushort4*)(xl + base) = l;
        hilo(v1.x, h.x, l.x); hilo(v1.y, h.y, l.y);
        hilo(v1.z, h.z, l.z); hilo(v1.w, h.w, l.w);
        *(ushort4*)(xh + base + 1024) = h; *(ushort4*)(xl + base + 1024) = l;
    } else if (c < 1216) {
        const float* src; unsigned short* dh; int off;
        if      (c < 1152) { src = W1; dh = W1h;         off = c - 1024; }
        else if (c < 1168) { src = M2; dh = C2h;         off = c - 1152; }
        else if (c < 1184) { src = R2; dh = C2h + 32768; off = c - 1168; }
        else if (c < 1200) { src = W3; dh = C3h;         off = c - 1184; }
        else               { src = R3; dh = C3h + 32768; off = c - 1200; }
        int base = off * 2048 + tid * 4;
        cv4h(dh, base,        *(const float4*)(src + base));
        cv4h(dh, base + 1024, *(const float4*)(src + base + 1024));
    } else if (c < 1344) {
        int gid = (c - 1216) * 256 + tid;     // 0..32767
        int i = gid >> 6, j = gid & 63;       // A3 (512 x 64)
        A3T[j * 512 + i] = A3[gid];
    } else {
        // G blocks: 1344..1407 -> G2y rows j; 1408..1471 -> G2r rows i
        int jrow = (c - 1344) & 63;
        const float* wv = (c < 1408) ? (M2 + jrow * 512) : (R2 + jrow * 512);
        float* G = (c < 1408) ? G2y : G2r;
        int jm = tid & 63, q = tid >> 6;
        const float* ap = A1 + (q * 128) * 64 + jm;
        const float* wp = wv + q * 128;
        float acc = 0.f;
        for (int cc = 0; cc < 128; ++cc)
            acc = fmaf(ap[cc * 64], wp[cc], acc);
        sh[q][jm] = acc;
        __syncthreads();
        if (tid < 64)
            G[tid * 64 + jrow] = (sh[0][tid] + sh[1][tid]) + (sh[2][tid] + sh[3][tid]);
    }
}

// ---------------------------------------------------------------------------
// MFMA GEMM, 128(M) x 64(N) tile, BK=64, 256 thr = 4 waves.
// AMODE: 2 = hi+lo iff bn>=512 (Wbig's LN cols).
// OM: 3 = split-K partials, col<512 bf16 at ld 512, col>=512 fp32 at ld 128.
// XOR-swizzled LDS (swizzle on global source idx; dest stays wave-uniform).
// ---------------------------------------------------------------------------
template<int AMODE, int OM>
__global__ __launch_bounds__(256, 4) void gemm128t(
        const unsigned short* __restrict__ Ah, const unsigned short* __restrict__ Al,
        const unsigned short* __restrict__ Wh,
        float* __restrict__ Cf, unsigned short* __restrict__ Cb,
        int N, int K, int Ks) {
    __shared__ __align__(16) unsigned short aH[8192];
    __shared__ __align__(16) unsigned short aL[AMODE ? 8192 : 16];
    __shared__ __align__(16) unsigned short wHs[4096];
    const int tid = threadIdx.x;
    const int wv  = tid >> 6;
    const int ln  = tid & 63;
    const int lm  = ln & 15;
    const int lq  = ln >> 4;
    const int bm  = blockIdx.y * 128;
    const int bn  = blockIdx.x * 64;
    const int k0  = blockIdx.z * Ks;
    const bool alo = (AMODE == 1) || (AMODE == 2 && bn >= 512);

    f4 acc[2][4] = {};

    for (int kt = 0; kt < Ks; kt += 64) {
        const int kg = k0 + kt;
        __syncthreads();
#pragma unroll
        for (int i = 0; i < 4; ++i) {
            int slot = i * 256 + wv * 64 + ln;
            int row  = slot >> 3;
            int ch   = (slot & 7) ^ (row & 7);
            size_t go = (size_t)(bm + row) * K + kg + ch * 8;
            async16(Ah + go, aH + slot * 8);
            if (alo) async16(Al + go, aL + slot * 8);
        }
#pragma unroll
        for (int i = 0; i < 2; ++i) {
            int slot = i * 256 + wv * 64 + ln;
            int row  = slot >> 3;
            int ch   = (slot & 7) ^ (row & 7);
            size_t go = (size_t)(bn + row) * K + kg + ch * 8;
            async16(Wh + go, wHs + slot * 8);
        }
        __syncthreads();

#pragma unroll
        for (int kk = 0; kk < 2; ++kk) {
            const int ck = kk * 4 + lq;          // 16B chunk index in k
            bf8 a_h[2], a_l[2], b_h[4];
#pragma unroll
            for (int t = 0; t < 2; ++t) {
                int r = wv * 32 + t * 16 + lm;
                a_h[t] = *(const bf8*)(aH + r * 64 + ((ck ^ (r & 7)) * 8));
                if (alo)
                    a_l[t] = *(const bf8*)(aL + r * 64 + ((ck ^ (r & 7)) * 8));
            }
#pragma unroll
            for (int u = 0; u < 4; ++u) {
                int rb = u * 16 + lm;
                b_h[u] = *(const bf8*)(wHs + rb * 64 + ((ck ^ (rb & 7)) * 8));
            }
#pragma unroll
            for (int t = 0; t < 2; ++t)
#pragma unroll
                for (int u = 0; u < 4; ++u) {
                    acc[t][u] = __builtin_amdgcn_mfma_f32_16x16x32_bf16(a_h[t], b_h[u], acc[t][u], 0, 0, 0);
                    if (alo)
                        acc[t][u] = __builtin_amdgcn_mfma_f32_16x16x32_bf16(a_l[t], b_h[u], acc[t][u], 0, 0, 0);
                }
        }
    }

    // C/D layout (verified): col = lane&15, row = quad*4 + reg
#pragma unroll
    for (int t = 0; t < 2; ++t)
#pragma unroll
        for (int u = 0; u < 4; ++u) {
            int row = bm + wv * 32 + t * 16 + lq * 4;
            int col = bn + u * 16 + lm;
#pragma unroll
            for (int r = 0; r < 4; ++r) {
                float v = acc[t][u][r];
                // OM == 3: split-K partials
                if (col < 512)
                    Cb[(size_t)blockIdx.z * ROWS * 512 + (size_t)(row + r) * 512 + col] = f2bf(v);
                else
                    Cf[(size_t)blockIdx.z * ROWS * 128 + (size_t)(row + r) * 128 + (col - 512)] = v;
            }
        }
}

// ---------------------------------------------------------------------------
// ptk: one row per wave. From C1 partials (bf16 x2): row reduces ->
// p = rstd*(S1 - mean*SU) + SBB  (== sum_c n*Bv with n = (y-mean)rstd*g+b).
// Then t = LN64( C2y + p*G2y[jm] ) and rsum = C2r + p*G2r[jm].
// ---------------------------------------------------------------------------
__global__ __launch_bounds__(256) void ptk(
        const unsigned short* __restrict__ C1b,   // 2 planes ROWS x 512 bf16
        const float* __restrict__ C2,             // 2 planes ROWS x 128 fp32
        const float* __restrict__ B1,
        const float* __restrict__ g1, const float* __restrict__ b1,
        const float* __restrict__ g2, const float* __restrict__ b2,
        const float* __restrict__ G2y, const float* __restrict__ G2r,
        float* __restrict__ t, float* __restrict__ rsum) {
    const int row = blockIdx.x * 4 + (threadIdx.x >> 6);
    const int l = threadIdx.x & 63;
    const int c = l * 8;
    const int jm = row & 63;
    const size_t rb0 = (size_t)row * 512 + c;
    ushort4 ua = *(const ushort4*)(C1b + rb0);
    ushort4 ub = *(const ushort4*)(C1b + rb0 + 4);
    ushort4 va = *(const ushort4*)(C1b + (size_t)ROWS * 512 + rb0);
    ushort4 vb = *(const ushort4*)(C1b + (size_t)ROWS * 512 + rb0 + 4);
    float y[8];
    y[0] = bf2f(ua.x) + bf2f(va.x); y[1] = bf2f(ua.y) + bf2f(va.y);
    y[2] = bf2f(ua.z) + bf2f(va.z); y[3] = bf2f(ua.w) + bf2f(va.w);
    y[4] = bf2f(ub.x) + bf2f(vb.x); y[5] = bf2f(ub.y) + bf2f(vb.y);
    y[6] = bf2f(ub.z) + bf2f(vb.z); y[7] = bf2f(ub.w) + bf2f(vb.w);
    float4 B0  = *(const float4*)(B1 + jm * 512 + c);
    float4 B1q = *(const float4*)(B1 + jm * 512 + c + 4);
    float4 gg0 = *(const float4*)(g1 + c), gg1 = *(const float4*)(g1 + c + 4);
    float4 bb0 = *(const float4*)(b1 + c), bb1 = *(const float4*)(b1 + c + 4);
    float Bv[8] = {B0.x, B0.y, B0.z, B0.w, B1q.x, B1q.y, B1q.z, B1q.w};
    float gv[8] = {gg0.x, gg0.y, gg0.z, gg0.w, gg1.x, gg1.y, gg1.z, gg1.w};
    float bv[8] = {bb0.x, bb0.y, bb0.z, bb0.w, bb1.x, bb1.y, bb1.z, bb1.w};
    float sum = 0.f, ssq = 0.f, S1 = 0.f, SU = 0.f, SBB = 0.f;
#pragma unroll
    for (int i = 0; i < 8; ++i) {
        float u = gv[i] * Bv[i];
        sum += y[i];
        ssq = fmaf(y[i], y[i], ssq);
        S1  = fmaf(y[i], u, S1);
        SU  += u;
        SBB = fmaf(bv[i], Bv[i], SBB);
    }
#pragma unroll
    for (int m = 1; m < 64; m <<= 1) {
        sum += __shfl_xor(sum, m, 64);
        ssq += __shfl_xor(ssq, m, 64);
        S1  += __shfl_xor(S1, m, 64);
        SU  += __shfl_xor(SU, m, 64);
        SBB += __shfl_xor(SBB, m, 64);
    }
    float mean = sum * (1.0f / 512.0f);
    float var  = ssq * (1.0f / 512.0f) - mean * mean;
    float rstd = rsqrtf(var + 1e-5f);
    float p = rstd * (S1 - mean * SU) + SBB;

    const size_t rb = (size_t)row * 128;
    float z  = C2[rb + l]      + C2[C2S + rb + l];
    float zr = C2[rb + 64 + l] + C2[C2S + rb + 64 + l];
    float v  = z  + p * G2y[jm * 64 + l];
    float rv = zr + p * G2r[jm * 64 + l];
    float s2 = v, q2 = v * v;
#pragma unroll
    for (int m = 1; m < 64; m <<= 1) {
        s2 += __shfl_xor(s2, m, 64);
        q2 += __shfl_xor(q2, m, 64);
    }
    float mean2 = s2 * (1.0f / 64.0f);
    float var2  = q2 * (1.0f / 64.0f) - mean2 * mean2;
    float rstd2 = rsqrtf(var2 + 1e-5f);
    t[row * 64 + l]    = (v - mean2) * rstd2 * g2[l] + b2[l];
    rsum[row * 64 + l] = rv;
}

// ---------------------------------------------------------------------------
// tsk2: Chebyshev-recurrence TS layer (verified).
// ---------------------------------------------------------------------------
__global__ __launch_bounds__(256) void tsk2(
        const float* __restrict__ t, const float* __restrict__ rsum,
        const float* __restrict__ P,
        unsigned short* __restrict__ Hh, unsigned short* __restrict__ Hl) {
    const int bid = blockIdx.x;
    const int i   = bid >> 3;
    const int sg  = bid & 7;
    const int w   = threadIdx.x >> 6;
    const int ln  = threadIdx.x & 63;       // j
    const int s0  = sg * 256 + w * 64;
    const int idx = i * 64 + ln;
    const float* pp = P + idx * 8;
    const float sf0 = (float)s0;

    float k2c[8], ca[8], cb[8];
#pragma unroll
    for (int g = 0; g < 8; ++g) {
        float pf   = (float)(idx * 8 + g + 2);
        float invp = __builtin_amdgcn_rcpf(pf);
        k2c[g] = 2.0f * __builtin_amdgcn_cosf(invp);     // 2*cos(2*pi/p)
        float q0 = floorf(sf0 * invp);
        float r0 = fmaf(-q0, pf, sf0);
        float f0 = r0 * invp; f0 -= floorf(f0);
        float c0 = __builtin_amdgcn_cosf(f0);
        float sf1 = sf0 + 1.0f;
        float q1 = floorf(sf1 * invp);
        float r1 = fmaf(-q1, pf, sf1);
        float f1 = r1 * invp; f1 -= floorf(f1);
        float c1 = __builtin_amdgcn_cosf(f1);
        float Pv = pp[g];
        ca[g] = Pv * c0;
        cb[g] = Pv * c1;
    }

    const int tb = s0 * 64 + ln;
    float t0c = t[tb], t1c = t[131072 + tb];
    float res0 = 0.f, res1 = 0.f;

    for (int st = 0; st < 64; st += 2) {
        float t0n  = t[tb + (st + 1) * 64];
        float t1n  = t[131072 + tb + (st + 1) * 64];
        float ws = ((ca[0] + ca[1]) + (ca[2] + ca[3]))
                 + ((ca[4] + ca[5]) + (ca[6] + ca[7]));
#pragma unroll
        for (int g = 0; g < 8; ++g) ca[g] = fmaf(k2c[g], cb[g], -ca[g]);
        float v0 = ws * t0c, v1 = ws * t1c;
#pragma unroll
        for (int m = 1; m < 64; m <<= 1) {
            v0 += __shfl_xor(v0, m, 64);
            v1 += __shfl_xor(v1, m, 64);
        }
        res0 = (ln == st) ? v0 : res0;
        res1 = (ln == st) ? v1 : res1;
        float t0n2 = t[tb + (st + 2) * 64];
        float t1n2 = t[131072 + tb + (st + 2) * 64];
        float ws2 = ((cb[0] + cb[1]) + (cb[2] + cb[3]))
                  + ((cb[4] + cb[5]) + (cb[6] + cb[7]));
#pragma unroll
        for (int g = 0; g < 8; ++g) cb[g] = fmaf(k2c[g], ca[g], -cb[g]);
        float v0b = ws2 * t0n, v1b = ws2 * t1n;
#pragma unroll
        for (int m = 1; m < 64; m <<= 1) {
            v0b += __shfl_xor(v0b, m, 64);
            v1b += __shfl_xor(v1b, m, 64);
        }
        res0 = (ln == st + 1) ? v0b : res0;
        res1 = (ln == st + 1) ? v1b : res1;
        t0c = t0n2; t1c = t1n2;
    }

    const int s = s0 + ln;
    {
        float v = res0 + rsum[(size_t)s * 64 + i];
        unsigned short h, l; hilo(v, h, l);
        Hh[(size_t)s * 64 + i] = h; Hl[(size_t)s * 64 + i] = l;
        float v1e = res1 + rsum[(size_t)(SEQ + s) * 64 + i];
        hilo(v1e, h, l);
        Hh[(size_t)(SEQ + s) * 64 + i] = h; Hl[(size_t)(SEQ + s) * 64 + i] = l;
    }
}

// ---------------------------------------------------------------------------
// g3ln: fused layer-3 GEMM + LN + rank-1 RN + residual + output.
// 256 blocks x 16 rows. Per block: C[16][1024] = h2[16 rows] @ [W3;R3]^T
// (K=64, hi+lo planes) accumulated into 64 KB LDS (fp32), then in-block
// 512-wide LN (ptk-style p formula), out = p*A3col(jm) + res.
// Replaces old gemm3 + lnrn; deletes C3n/C3r (24 MB of traffic).
// W staged per-phase (4 phases x 256 rows x 64 k = 32 KB); epilogue LDS reads
// use scalar b32 at lane-stride-1 (conflict-free) instead of b128 (16-way).
// ---------------------------------------------------------------------------
__global__ __launch_bounds__(256) void g3ln(
        const unsigned short* __restrict__ Hh, const unsigned short* __restrict__ Hl,
        const unsigned short* __restrict__ Wc3h,   // [1024][64] bf16 (W3;R3)
        const float* __restrict__ g3, const float* __restrict__ b3,
        const float* __restrict__ B3, const float* __restrict__ A3T,
        float* __restrict__ outf) {
    __shared__ __align__(16) unsigned short aH[1024];   // 16 x 64 hi
    __shared__ __align__(16) unsigned short aL[1024];   // 16 x 64 lo
    __shared__ __align__(16) unsigned short wS[16384];  // 256 x 64 (one phase)
    __shared__ float cS[16 * 1024];                     // 64 KB C tile
    const int tid = threadIdx.x;
    const int wv  = tid >> 6;
    const int ln  = tid & 63;
    const int lm  = ln & 15;
    const int lq  = ln >> 4;
    const int r0  = blockIdx.x * 16;

    // stage A (h2 rows r0..r0+15): waves 0,1 -> hi slots 0..127; 2,3 -> lo
    {
        int slot = (wv & 1) * 64 + ln;
        int row  = slot >> 3;
        int ch   = (slot & 7) ^ (row & 7);
        size_t go = (size_t)(r0 + row) * 64 + ch * 8;
        if (wv < 2) async16(Hh + go, aH + slot * 8);
        else        async16(Hl + go, aL + slot * 8);
    }

    bf8 ah[2], al[2];
    for (int q = 0; q < 4; ++q) {
        // stage W phase q: local rows lr 0..255 -> W row (lr>>6)*256 + q*64 + (lr&63)
#pragma unroll
        for (int i = 0; i < 8; ++i) {
            int slot = i * 256 + tid;
            int lr   = slot >> 3;
            int ch   = (slot & 7) ^ (lr & 7);
            int grow = (lr >> 6) * 256 + q * 64 + (lr & 63);
            size_t go = (size_t)grow * 64 + ch * 8;
            async16(Wc3h + go, wS + slot * 8);
        }
        __syncthreads();   // drains vmcnt: A (q==0) + W_q staged
        if (q == 0) {
#pragma unroll
            for (int kk = 0; kk < 2; ++kk) {
                int ck = kk * 4 + lq;
                ah[kk] = *(const bf8*)(aH + lm * 64 + ((ck ^ (lm & 7)) * 8));
                al[kk] = *(const bf8*)(aL + lm * 64 + ((ck ^ (lm & 7)) * 8));
            }
        }
        f4 acc[4] = {};
#pragma unroll
        for (int kk = 0; kk < 2; ++kk) {
            int ck = kk * 4 + lq;
            bf8 bh[4];
#pragma unroll
            for (int u = 0; u < 4; ++u) {
                int lr = wv * 64 + u * 16 + lm;
                bh[u] = *(const bf8*)(wS + lr * 64 + ((ck ^ (lr & 7)) * 8));
            }
#pragma unroll
            for (int u = 0; u < 4; ++u) {
                acc[u] = __builtin_amdgcn_mfma_f32_16x16x32_bf16(ah[kk], bh[u], acc[u], 0, 0, 0);
                acc[u] = __builtin_amdgcn_mfma_f32_16x16x32_bf16(al[kk], bh[u], acc[u], 0, 0, 0);
            }
        }
        // C/D layout: col = u*16 + lm (+ wave/phase base), row = lq*4 + r
#pragma unroll
        for (int u = 0; u < 4; ++u) {
            int col = wv * 256 + q * 64 + u * 16 + lm;
#pragma unroll
            for (int r = 0; r < 4; ++r)
                cS[(lq * 4 + r) * 1024 + col] = acc[u][r];
        }
        __syncthreads();   // wS reuse + cS visibility
    }

    // epilogue: wave wv owns rows wv*4 .. wv*4+3
    for (int rr = 0; rr < 4; ++rr) {
        int row  = wv * 4 + rr;
        int grow = r0 + row;
        int jm   = grow & 63;
        const float* Bp = B3  + jm * 512;
        const float* Ap = A3T + jm * 512;
        float sum = 0.f, ssq = 0.f, S1 = 0.f, SU = 0.f, SBB = 0.f;
#pragma unroll
        for (int k = 0; k < 8; ++k) {
            int col = ln + k * 64;
            float y  = cS[row * 1024 + col];
            float Bv = Bp[col];
            float gv = g3[col];
            float bv = b3[col];
            float u = gv * Bv;
            sum += y;
            ssq = fmaf(y, y, ssq);
            S1  = fmaf(y, u, S1);
            SU  += u;
            SBB = fmaf(bv, Bv, SBB);
        }
#pragma unroll
        for (int m = 1; m < 64; m <<= 1) {
            sum += __shfl_xor(sum, m, 64);
            ssq += __shfl_xor(ssq, m, 64);
            S1  += __shfl_xor(S1, m, 64);
            SU  += __shfl_xor(SU, m, 64);
            SBB += __shfl_xor(SBB, m, 64);
        }
        float mean = sum * (1.0f / 512.0f);
        float var  = ssq * (1.0f / 512.0f) - mean * mean;
        float rstd = rsqrtf(var + 1e-5f);
        float p = rstd * (S1 - mean * SU) + SBB;
#pragma unroll
        for (int k = 0; k < 8; ++k) {
            int col = ln + k * 64;
            float res = cS[row * 1024 + 512 + col];
            outf[(size_t)grow * 512 + col] = fmaf(p, Ap[col], res);
        }
    }
}

// ---------------------------------------------------------------------------
extern "C" void kernel_launch(void* const* d_in, const int* in_sizes, int n_in,
                              void* d_out, int out_size, void* d_ws, size_t ws_size,
                              hipStream_t stream) {
    (void)in_sizes; (void)n_in; (void)out_size; (void)ws_size;
    const float* x  = (const float*)d_in[0];
    const float* W1 = (const float*)d_in[1];
    const float* g1 = (const float*)d_in[2];
    const float* b1 = (const float*)d_in[3];
    const float* A1 = (const float*)d_in[4];
    const float* B1 = (const float*)d_in[5];
    const float* M2 = (const float*)d_in[6];
    const float* g2 = (const float*)d_in[7];
    const float* b2 = (const float*)d_in[8];
    const float* P2 = (const float*)d_in[9];
    const float* R2 = (const float*)d_in[10];
    const float* W3 = (const float*)d_in[11];
    const float* g3 = (const float*)d_in[12];
    const float* b3 = (const float*)d_in[13];
    const float* A3 = (const float*)d_in[14];
    const float* B3 = (const float*)d_in[15];
    const float* R3 = (const float*)d_in[16];

    float* ws = (float*)d_ws;
    float* C2   = ws;                  // 2 x 524,288 fp32 partials (y|res, ld 128)
    float* t    = ws + 4194304;        // 262,144
    float* rsum = ws + 4456448;        // 262,144 (must follow t: overrun pad)
    float* G2y  = ws + 4718592;        // 4,096
    float* G2r  = ws + 4722688;        // 4,096
    float* A3T  = ws + 4751360;        // 32,768
    unsigned short* us = (unsigned short*)(ws + 4784128);
    unsigned short* xh   = us;                  // 2,097,152
    unsigned short* xl   = us + 2097152;        // 2,097,152
    unsigned short* W1h  = us + 6291456;        // 262,144 (rows 0..511 of Wbig)
    unsigned short* Wc2h = us + 6553600;        // 65,536  (rows 512..639 of Wbig)
    unsigned short* Wc3h = us + 6619136;        // 65,536 (1024 x 64)
    unsigned short* h2h  = us + 6684672;        // 262,144
    unsigned short* h2l  = us + 6946816;        // 262,144
    unsigned short* C1b  = us + 7208960;        // 2 x 2,097,152 (bf16 partials)

    dim3 blk(256);

    // 0) convert x (hi+lo) + weights (hi) + A3 transpose + G2y/G2r
    convk<<<1472, blk, 0, stream>>>(x, W1, M2, R2, W3, R3, A1, A3,
                                    xh, xl, W1h, Wc2h, Wc3h, A3T, G2y, G2r);

    // 1) merged GEMM: [C1 | C2y | C2r] = x @ [W1; M2; R2]^T  (N=640, split-K=2)
    gemm128t<2, 3><<<dim3(10, 32, 2), blk, 0, stream>>>(
        xh, xl, W1h, C2, C1b, 640, 512, 256);

    // 2) p from C1 row-reduces; t = LN64(C2y + p*G2y); rsum = C2r + p*G2r
    ptk<<<1024, blk, 0, stream>>>(C1b, C2, B1, g1, b1, g2, b2, G2y, G2r, t, rsum);

    // 3) TS Chebyshev recurrence -> h2 (hi/lo)
    tsk2<<<512, blk, 0, stream>>>(t, rsum, P2, h2h, h2l);

    // 4) fused layer-3: GEMM(K=64, hi+lo) + LN + rank-1 + residual -> out
    g3ln<<<256, blk, 0, stream>>>(h2h, h2l, Wc3h, g3, b3, B3, A3T, (float*)d_out);
}